// Round 5
// baseline (431.044 us; speedup 1.0000x reference)
//
#include <hip/hip_runtime.h>

#define DD 128
#define HH 64
#define RR 4
#define NT 256          // block size
#define DGRID 512       // persistent grid: 2 blocks/CU exactly (residency guaranteed)
#define DPART 128       // DGRID / RR tile-stride per relation (dense phase)

typedef __attribute__((ext_vector_type(8))) __bf16 bf16x8;
typedef __attribute__((ext_vector_type(4))) __bf16 bf16x4;
typedef __attribute__((ext_vector_type(4))) float f32x4;

// LDS row strides (bf16 elements). Odd multiples of 8 -> conflict-free b128 r/w.
#define SK128 136   // K=128 rows (+8 pad)
#define SK64  72    // K=64 rows  (+8 pad)
#define ABLK  2176  // per-wave act block

// dense-phase dynamic LDS layout (elements)
#define O_W1  0                    // 64 x 136 = 8704
#define O_W2  8704                 // 64 x 72  = 4608
#define O_W3  13312                // 128 x 72 = 9216
#define O_WP  22528                // 64 x 136 = 8704
#define O_ACT 31232                // 4 x 2176 = 8704
#define DSMEM_ELEMS 39936          // 79872 B -> 2 blocks/CU
// node-phase layout (same buffer, after grid barrier)
#define N_W1  0
#define N_W2  8704
#define N_W3  13312
#define N_ACT 22528                // + 4 x 2176 -> 31232 <= DSMEM_ELEMS

// global bf16 weight pool offsets (elements), all matrices [n][k] row-major
#define W1T_OFF 0        // [R][64][128]
#define W2T_OFF 32768    // [R][64][64]
#define W3T_OFF 49152    // [R][128][64]
#define WPT_OFF 81920    // [R][64][128]  (Wn1 slice 1+r)
#define WN1_OFF 114688   // [64][128]     (Wn1 slice 0)
#define WN2_OFF 122880   // [64][64]
#define WN3_OFF 126976   // [128][64]
#define WT_TOTAL 135168

#define MFMA(a, b, c) __builtin_amdgcn_mfma_f32_16x16x32_bf16(a, b, c, 0, 0, 0)

// ca column permutation: stored col' = ln*4 + nt -> 8B store in PROJ, 8B load in gather.

// ---- manual grid barrier (normal launch; all 512 blocks co-resident by construction).
// Monotonic phase counter zeroed by host memset each run. Device-scope fences per G16.
__device__ __forceinline__ void gbar(int* bar, int target) {
    __syncthreads();
    if (threadIdx.x == 0) {
        __threadfence();   // release: drain this block's stores to the coherent point
        __hip_atomic_fetch_add(bar, 1, __ATOMIC_ACQ_REL, __HIP_MEMORY_SCOPE_AGENT);
        while (__hip_atomic_load(bar, __ATOMIC_ACQUIRE, __HIP_MEMORY_SCOPE_AGENT) < target)
            __builtin_amdgcn_s_sleep(2);
        __threadfence();   // acquire: invalidate L1/L2 so the block reads fresh data
    }
    __syncthreads();
}

// Stage [ROWS][COLS] row-major global -> LDS rows with padded STRIDE.
template<int ROWS, int COLS, int STRIDE, int BLK>
__device__ __forceinline__ void stageRM(const __bf16* __restrict__ g, __bf16* s, int tid) {
    constexpr int CH = COLS / 8;
    constexpr int TOT = ROWS * CH;
    #pragma unroll
    for (int i = tid; i < TOT; i += BLK) {
        const int row = i / CH, c8 = i % CH;
        *(bf16x8*)(s + row * STRIDE + c8 * 8) = *(const bf16x8*)(g + row * COLS + c8 * 8);
    }
}

// ================= single persistent kernel: all phases, 5 manual grid barriers =================
__global__ __launch_bounds__(NT, 2) void k_mega(
    const float* __restrict__ nf,
    const int* __restrict__ es, const int* __restrict__ ed, const int* __restrict__ et,
    const float* __restrict__ Wr1, const float* __restrict__ br1,
    const float* __restrict__ Wr2, const float* __restrict__ br2,
    const float* __restrict__ Wr3, const float* __restrict__ br3,
    const float* __restrict__ Wn1, const float* __restrict__ bn1,
    const float* __restrict__ Wn2, const float* __restrict__ bn2,
    const float* __restrict__ Wn3, const float* __restrict__ bn3,
    __bf16* __restrict__ wt, __bf16* __restrict__ ca,
    int* bar, int* __restrict__ dstCnt, int* __restrict__ dstCursor,
    int* __restrict__ rowStart, int* __restrict__ blkSum,
    int* __restrict__ csrKey, float* __restrict__ out,
    int Nn, int E, int NB)
{
    extern __shared__ __bf16 smem[];

    const int tid  = threadIdx.x;
    const int gtid = blockIdx.x * NT + tid;
    const int GSZ  = DGRID * NT;                  // 131072
    const int w = tid >> 6;
    const int lane = tid & 63;
    const int ln = lane & 15, qd = lane >> 4;
    const int m0 = w << 4;

    // ---------- P0: weight transpose/convert (dstCnt + bar zeroed by host memset) ----------
    for (int i = gtid; i < WT_TOTAL; i += GSZ) {
        if (i < 32768) {                                  // Wr1 [r][k128][n64] -> [r][n][k]
            int r = i >> 13, k = (i >> 6) & 127, n = i & 63;
            wt[W1T_OFF + r * 8192 + n * 128 + k] = (__bf16)Wr1[i];
        } else if (i < 49152) {                           // Wr2 [r][k64][n64]
            int j = i - 32768; int r = j >> 12, k = (j >> 6) & 63, n = j & 63;
            wt[W2T_OFF + r * 4096 + n * 64 + k] = (__bf16)Wr2[j];
        } else if (i < 81920) {                           // Wr3 [r][k64][n128]
            int j = i - 49152; int r = j >> 13, k = (j >> 7) & 63, n = j & 127;
            wt[W3T_OFF + r * 8192 + n * 64 + k] = (__bf16)Wr3[j];
        } else if (i < 122880) {                          // Wn1 [(R+1)*128][64]
            int j = i - 81920; int row = j >> 6, n = j & 63;
            int s = row >> 7, k = row & 127;
            float v = Wn1[j];
            if (s == 0) wt[WN1_OFF + n * 128 + k] = (__bf16)v;
            else        wt[WPT_OFF + (s - 1) * 8192 + n * 128 + k] = (__bf16)v;
        } else if (i < 126976) {                          // Wn2 [k64][n64]
            int j = i - 122880; int k = j >> 6, n = j & 63;
            wt[WN2_OFF + n * 64 + k] = (__bf16)Wn2[j];
        } else {                                          // Wn3 [k64][n128]
            int j = i - 126976; int k = j >> 7, n = j & 127;
            wt[WN3_OFF + n * 64 + k] = (__bf16)Wn3[j];
        }
    }
    gbar(bar, DGRID * 1);   // ---- G1: weights + zeroed hist visible

    // ---------- P1: dst histogram (atomics) + DENSE message/projection ----------
    for (int i = gtid; i < E; i += GSZ) atomicAdd(&dstCnt[ed[i]], 1);
    {
        const int r    = blockIdx.x & 3;
        const int part = blockIdx.x >> 2;
        __bf16* act = smem + O_ACT + w * ABLK;

        stageRM<64, 128, SK128, NT>(wt + W1T_OFF + r * 8192, smem + O_W1, tid);
        stageRM<64,  64, SK64 , NT>(wt + W2T_OFF + r * 4096, smem + O_W2, tid);
        stageRM<128, 64, SK64 , NT>(wt + W3T_OFF + r * 8192, smem + O_W3, tid);
        stageRM<64, 128, SK128, NT>(wt + WPT_OFF + r * 8192, smem + O_WP, tid);

        float bv1[4], bv2[4], bv3[8];
        #pragma unroll
        for (int nt = 0; nt < 4; nt++) {
            bv1[nt] = br1[r * HH + nt * 16 + ln];
            bv2[nt] = br2[r * HH + nt * 16 + ln];
        }
        #pragma unroll
        for (int nt = 0; nt < 8; nt++) bv3[nt] = br3[r * DD + nt * 16 + ln];

        const int T = (Nn + 63) >> 6;
        const int mx = tid >> 2, qx = tid & 3;
        __bf16* xr = act + (mx & 15) * SK128 + 32 * qx;

        float4 xv[8];
        int t = part;
        if (t < T) {
            const int node = min(t * 64 + mx, Nn - 1);
            const float4* rp = (const float4*)(nf + (size_t)node * DD) + 8 * qx;
            #pragma unroll
            for (int j = 0; j < 8; j++) xv[j] = rp[j];
        }
        __syncthreads();   // weights ready (block-local)

        for (; t < T; t += DPART) {
            const int nb0 = t * 64;
            #pragma unroll
            for (int jj = 0; jj < 4; jj++) {
                float4 v0 = xv[2 * jj], v1 = xv[2 * jj + 1];
                bf16x8 p;
                p[0] = (__bf16)v0.x; p[1] = (__bf16)v0.y; p[2] = (__bf16)v0.z; p[3] = (__bf16)v0.w;
                p[4] = (__bf16)v1.x; p[5] = (__bf16)v1.y; p[6] = (__bf16)v1.z; p[7] = (__bf16)v1.w;
                *(bf16x8*)(xr + 8 * jj) = p;
            }
            bf16x8 ax[4];
            #pragma unroll
            for (int i = 0; i < 4; i++)
                ax[i] = *(const bf16x8*)(act + ln * SK128 + i * 32 + 8 * qd);

            const int tn = t + DPART;
            if (tn < T) {
                const int node = min(tn * 64 + mx, Nn - 1);
                const float4* rp = (const float4*)(nf + (size_t)node * DD) + 8 * qx;
                #pragma unroll
                for (int j = 0; j < 8; j++) xv[j] = rp[j];
            }

            // GEMM1: K=128 N=64
            {
                f32x4 c[4] = {};
                #pragma unroll
                for (int kk = 0; kk < 4; kk++)
                    #pragma unroll
                    for (int nt = 0; nt < 4; nt++) {
                        bf16x8 b = *(const bf16x8*)(smem + O_W1 + (nt * 16 + ln) * SK128 + kk * 32 + 8 * qd);
                        c[nt] = MFMA(ax[kk], b, c[nt]);
                    }
                #pragma unroll
                for (int nt = 0; nt < 4; nt++)
                    #pragma unroll
                    for (int rg = 0; rg < 4; rg++) {
                        float v = c[nt][rg] + bv1[nt];
                        act[(qd * 4 + rg) * SK64 + nt * 16 + ln] = (__bf16)fmaxf(v, 0.f);
                    }
            }
            // GEMM2: K=64
            {
                bf16x8 a0 = *(const bf16x8*)(act + ln * SK64 + 0 + 8 * qd);
                bf16x8 a1 = *(const bf16x8*)(act + ln * SK64 + 32 + 8 * qd);
                f32x4 c[4] = {};
                #pragma unroll
                for (int nt = 0; nt < 4; nt++) {
                    bf16x8 b0 = *(const bf16x8*)(smem + O_W2 + (nt * 16 + ln) * SK64 + 0 + 8 * qd);
                    bf16x8 b1 = *(const bf16x8*)(smem + O_W2 + (nt * 16 + ln) * SK64 + 32 + 8 * qd);
                    c[nt] = MFMA(a0, b0, c[nt]);
                    c[nt] = MFMA(a1, b1, c[nt]);
                }
                #pragma unroll
                for (int nt = 0; nt < 4; nt++)
                    #pragma unroll
                    for (int rg = 0; rg < 4; rg++) {
                        float v = c[nt][rg] + bv2[nt];
                        act[(qd * 4 + rg) * SK64 + nt * 16 + ln] = (__bf16)fmaxf(v, 0.f);
                    }
            }
            // GEMM3: K=64 N=128
            {
                bf16x8 a0 = *(const bf16x8*)(act + ln * SK64 + 0 + 8 * qd);
                bf16x8 a1 = *(const bf16x8*)(act + ln * SK64 + 32 + 8 * qd);
                f32x4 c[8];
                #pragma unroll
                for (int nt = 0; nt < 8; nt++) {
                    bf16x8 b0 = *(const bf16x8*)(smem + O_W3 + (nt * 16 + ln) * SK64 + 0 + 8 * qd);
                    bf16x8 b1 = *(const bf16x8*)(smem + O_W3 + (nt * 16 + ln) * SK64 + 32 + 8 * qd);
                    f32x4 acc = {};
                    acc = MFMA(a0, b0, acc);
                    acc = MFMA(a1, b1, acc);
                    c[nt] = acc;
                }
                #pragma unroll
                for (int nt = 0; nt < 8; nt++)
                    #pragma unroll
                    for (int rg = 0; rg < 4; rg++) {
                        float v = c[nt][rg] + bv3[nt];
                        act[(qd * 4 + rg) * SK128 + nt * 16 + ln] = (__bf16)fmaxf(v, 0.f);
                    }
            }
            // PROJ: K=128 N=64 -> ca (permuted col ln*4+nt, 8B stores)
            {
                bf16x8 am[4];
                #pragma unroll
                for (int i = 0; i < 4; i++)
                    am[i] = *(const bf16x8*)(act + ln * SK128 + i * 32 + 8 * qd);
                f32x4 c[4] = {};
                #pragma unroll
                for (int kk = 0; kk < 4; kk++)
                    #pragma unroll
                    for (int nt = 0; nt < 4; nt++) {
                        bf16x8 b = *(const bf16x8*)(smem + O_WP + (nt * 16 + ln) * SK128 + kk * 32 + 8 * qd);
                        c[nt] = MFMA(am[kk], b, c[nt]);
                    }
                #pragma unroll
                for (int rg = 0; rg < 4; rg++) {
                    const int node = nb0 + m0 + qd * 4 + rg;
                    if (node < Nn) {
                        bf16x4 v;
                        v[0] = (__bf16)c[0][rg]; v[1] = (__bf16)c[1][rg];
                        v[2] = (__bf16)c[2][rg]; v[3] = (__bf16)c[3][rg];
                        *(bf16x4*)(ca + ((size_t)r * Nn + node) * HH + ln * 4) = v;
                    }
                }
            }
        }
    }
    gbar(bar, DGRID * 2);   // ---- G2: hist + ca complete

    // ---------- P2: per-chunk sums (blocks 0..NB-1, chunk = 1024 nodes) ----------
    if (blockIdx.x < NB) {
        int* iw = (int*)smem;
        const int g = blockIdx.x * 1024 + tid * 4;
        int s = 0;
        if (g + 3 < Nn) { int4 v = *(const int4*)(dstCnt + g); s = v.x + v.y + v.z + v.w; }
        else { for (int k = 0; k < 4; k++) if (g + k < Nn) s += dstCnt[g + k]; }
        for (int off = 32; off > 0; off >>= 1) s += __shfl_down(s, off);
        __syncthreads();                // claim LDS (dense weights dead)
        if ((tid & 63) == 0) iw[tid >> 6] = s;
        __syncthreads();
        if (tid == 0) blkSum[blockIdx.x] = iw[0] + iw[1] + iw[2] + iw[3];
    }
    gbar(bar, DGRID * 3);   // ---- G3: blkSum visible

    // ---------- P3: chunk-blocks redundantly scan blkSum; write rowStart/dstCursor ----------
    if (blockIdx.x < NB) {
        int* iw = (int*)smem;           // iw[0..3]=wave sums, iw[4]=chunk base
        if (tid < 64) {
            int s = (tid < NB) ? blkSum[tid] : 0;
            int sc = s;
            #pragma unroll
            for (int off = 1; off < 64; off <<= 1) { int u = __shfl_up(sc, off); if (tid >= off) sc += u; }
            int ex = (blockIdx.x == 0) ? 0 : __shfl(sc, blockIdx.x - 1);
            if (tid == 0) iw[4] = ex;
        }
        __syncthreads();
        const int e0base = iw[4];

        const int g = blockIdx.x * 1024 + tid * 4;
        int4 v = {0, 0, 0, 0};
        bool full = (g + 3 < Nn);
        if (full) v = *(const int4*)(dstCnt + g);
        else {
            if (g     < Nn) v.x = dstCnt[g];
            if (g + 1 < Nn) v.y = dstCnt[g + 1];
            if (g + 2 < Nn) v.z = dstCnt[g + 2];
        }
        int s = v.x + v.y + v.z + v.w;
        int lane2 = tid & 63, wv = tid >> 6;
        int sc = s;
        #pragma unroll
        for (int off = 1; off < 64; off <<= 1) { int u = __shfl_up(sc, off); if (lane2 >= off) sc += u; }
        if (lane2 == 63) iw[wv] = sc;
        __syncthreads();
        int wadd = 0;
        for (int i = 0; i < wv; i++) wadd += iw[i];
        int e0 = e0base + wadd + sc - s;
        int4 rs; rs.x = e0; rs.y = e0 + v.x; rs.z = rs.y + v.y; rs.w = rs.z + v.z;
        if (full) { *(int4*)(rowStart + g) = rs; *(int4*)(dstCursor + g) = rs; }
        else {
            int a[4] = {rs.x, rs.y, rs.z, rs.w};
            for (int k = 0; k < 4; k++) if (g + k < Nn) { rowStart[g + k] = a[k]; dstCursor[g + k] = a[k]; }
        }
    }
    if (gtid == 0) rowStart[Nn] = E;
    gbar(bar, DGRID * 4);   // ---- G4: rowStart/dstCursor visible

    // ---------- P4: CSR fill ----------
    for (int i = gtid; i < E; i += GSZ) {
        int sl = atomicAdd(&dstCursor[ed[i]], 1);
        csrKey[sl] = et[i] * Nn + es[i];
    }
    gbar(bar, DGRID * 5);   // ---- G5: csrKey complete

    // ---------- P5: node updater MLP (stage WN once, grid-stride tiles) ----------
    {
        __bf16* act = smem + N_ACT + w * ABLK;
        stageRM<64, 128, SK128, NT>(wt + WN1_OFF, smem + N_W1, tid);
        stageRM<64,  64, SK64 , NT>(wt + WN2_OFF, smem + N_W2, tid);
        stageRM<128, 64, SK64 , NT>(wt + WN3_OFF, smem + N_W3, tid);

        float bv1[4], bv2[4], bv3[8];
        #pragma unroll
        for (int nt = 0; nt < 4; nt++) { bv1[nt] = bn1[nt * 16 + ln]; bv2[nt] = bn2[nt * 16 + ln]; }
        #pragma unroll
        for (int nt = 0; nt < 8; nt++) bv3[nt] = bn3[nt * 16 + ln];

        const int T = (Nn + 63) >> 6;
        const int mx = tid >> 2, qx = tid & 3;
        __bf16* xr = act + (mx & 15) * SK128 + 32 * qx;
        __syncthreads();   // WN weights ready (block-local)

        for (int t = blockIdx.x; t < T; t += DGRID) {
            const int nb0 = t * 64;
            // relu(X) rows -> act (wave-local)
            {
                const int node = min(nb0 + mx, Nn - 1);
                const float4* rp = (const float4*)(nf + (size_t)node * DD) + 8 * qx;
                #pragma unroll
                for (int jj = 0; jj < 4; jj++) {
                    float4 v0 = rp[2 * jj], v1 = rp[2 * jj + 1];
                    bf16x8 p;
                    p[0] = (__bf16)fmaxf(v0.x, 0.f); p[1] = (__bf16)fmaxf(v0.y, 0.f);
                    p[2] = (__bf16)fmaxf(v0.z, 0.f); p[3] = (__bf16)fmaxf(v0.w, 0.f);
                    p[4] = (__bf16)fmaxf(v1.x, 0.f); p[5] = (__bf16)fmaxf(v1.y, 0.f);
                    p[6] = (__bf16)fmaxf(v1.z, 0.f); p[7] = (__bf16)fmaxf(v1.w, 0.f);
                    *(bf16x8*)(xr + 8 * jj) = p;
                }
            }
            bf16x8 ax[4];
            #pragma unroll
            for (int i = 0; i < 4; i++)
                ax[i] = *(const bf16x8*)(act + ln * SK128 + i * 32 + 8 * qd);

            // CSR gather (permuted ca: one 8B load per lane per edge; 4 rows x 2-edge ILP)
            float agg[4][4] = {};
            {
                const int base = nb0 + m0 + qd * 4;
                int rs[5];
                #pragma unroll
                for (int j = 0; j < 5; j++) rs[j] = rowStart[min(base + j, Nn)];
                int cur[4];
                #pragma unroll
                for (int rg = 0; rg < 4; rg++) cur[rg] = rs[rg];
                const __bf16* cab = ca + ln * 4;

                while (true) {
                    int k0[4], k1[4];
                    bool v0[4], v1[4];
                    bool any = false;
                    #pragma unroll
                    for (int rg = 0; rg < 4; rg++) {
                        const int c0 = cur[rg], e1 = rs[rg + 1];
                        v0[rg] = c0 < e1;
                        v1[rg] = c0 + 1 < e1;
                        if (v0[rg]) k0[rg] = csrKey[c0];
                        if (v1[rg]) k1[rg] = csrKey[c0 + 1];
                        cur[rg] = c0 + (v0[rg] ? 1 : 0) + (v1[rg] ? 1 : 0);
                        any |= v0[rg];
                    }
                    if (!any) break;
                    #pragma unroll
                    for (int rg = 0; rg < 4; rg++) {
                        if (v0[rg]) {
                            const bf16x4 x = *(const bf16x4*)(cab + (size_t)k0[rg] * HH);
                            agg[rg][0] += (float)x[0]; agg[rg][1] += (float)x[1];
                            agg[rg][2] += (float)x[2]; agg[rg][3] += (float)x[3];
                        }
                        if (v1[rg]) {
                            const bf16x4 x = *(const bf16x4*)(cab + (size_t)k1[rg] * HH);
                            agg[rg][0] += (float)x[0]; agg[rg][1] += (float)x[1];
                            agg[rg][2] += (float)x[2]; agg[rg][3] += (float)x[3];
                        }
                    }
                }
            }

            // GEMM1n: K=128 N=64 (+agg)
            {
                f32x4 c[4] = {};
                #pragma unroll
                for (int kk = 0; kk < 4; kk++)
                    #pragma unroll
                    for (int nt = 0; nt < 4; nt++) {
                        bf16x8 b = *(const bf16x8*)(smem + N_W1 + (nt * 16 + ln) * SK128 + kk * 32 + 8 * qd);
                        c[nt] = MFMA(ax[kk], b, c[nt]);
                    }
                #pragma unroll
                for (int nt = 0; nt < 4; nt++)
                    #pragma unroll
                    for (int rg = 0; rg < 4; rg++) {
                        float v = c[nt][rg] + bv1[nt] + agg[rg][nt];
                        act[(qd * 4 + rg) * SK64 + nt * 16 + ln] = (__bf16)fmaxf(v, 0.f);
                    }
            }
            // GEMM2n: K=64
            {
                bf16x8 a0 = *(const bf16x8*)(act + ln * SK64 + 0 + 8 * qd);
                bf16x8 a1 = *(const bf16x8*)(act + ln * SK64 + 32 + 8 * qd);
                f32x4 c[4] = {};
                #pragma unroll
                for (int nt = 0; nt < 4; nt++) {
                    bf16x8 b0 = *(const bf16x8*)(smem + N_W2 + (nt * 16 + ln) * SK64 + 0 + 8 * qd);
                    bf16x8 b1 = *(const bf16x8*)(smem + N_W2 + (nt * 16 + ln) * SK64 + 32 + 8 * qd);
                    c[nt] = MFMA(a0, b0, c[nt]);
                    c[nt] = MFMA(a1, b1, c[nt]);
                }
                #pragma unroll
                for (int nt = 0; nt < 4; nt++)
                    #pragma unroll
                    for (int rg = 0; rg < 4; rg++) {
                        float v = c[nt][rg] + bv2[nt];
                        act[(qd * 4 + rg) * SK64 + nt * 16 + ln] = (__bf16)fmaxf(v, 0.f);
                    }
            }
            // GEMM3n: K=64 N=128 -> out
            {
                bf16x8 a0 = *(const bf16x8*)(act + ln * SK64 + 0 + 8 * qd);
                bf16x8 a1 = *(const bf16x8*)(act + ln * SK64 + 32 + 8 * qd);
                f32x4 c[8];
                #pragma unroll
                for (int nt = 0; nt < 8; nt++) {
                    bf16x8 b0 = *(const bf16x8*)(smem + N_W3 + (nt * 16 + ln) * SK64 + 0 + 8 * qd);
                    bf16x8 b1 = *(const bf16x8*)(smem + N_W3 + (nt * 16 + ln) * SK64 + 32 + 8 * qd);
                    f32x4 acc = {};
                    acc = MFMA(a0, b0, acc);
                    acc = MFMA(a1, b1, acc);
                    c[nt] = acc;
                }
                #pragma unroll
                for (int rg = 0; rg < 4; rg++) {
                    const int node = nb0 + m0 + qd * 4 + rg;
                    if (node < Nn) {
                        float* op = out + (size_t)node * DD;
                        #pragma unroll
                        for (int nt = 0; nt < 8; nt++)
                            op[nt * 16 + ln] = c[nt][rg] + bv3[nt];
                    }
                }
            }
        }
    }
}

extern "C" void kernel_launch(void* const* d_in, const int* in_sizes, int n_in,
                              void* d_out, int out_size, void* d_ws, size_t ws_size,
                              hipStream_t stream) {
    const float* nf  = (const float*)d_in[0];
    const int*   es  = (const int*)d_in[1];
    const int*   ed  = (const int*)d_in[2];
    const int*   et  = (const int*)d_in[3];
    const float* Wr1 = (const float*)d_in[4];
    const float* br1 = (const float*)d_in[5];
    const float* Wr2 = (const float*)d_in[6];
    const float* br2 = (const float*)d_in[7];
    const float* Wr3 = (const float*)d_in[8];
    const float* br3 = (const float*)d_in[9];
    const float* Wn1 = (const float*)d_in[10];
    const float* bn1 = (const float*)d_in[11];
    const float* Wn2 = (const float*)d_in[12];
    const float* bn2 = (const float*)d_in[13];
    const float* Wn3 = (const float*)d_in[14];
    const float* bn3 = (const float*)d_in[15];
    float* out = (float*)d_out;

    int Nn = in_sizes[0] / DD;   // 50000
    int E  = in_sizes[1];        // 200000
    int NB = (Nn + 1023) / 1024; // 49

    int* p = (int*)d_ws;
    int* bar       = p;                 p += 4;       // barrier counter (zeroed)
    int* dstCnt    = p;                 p += Nn;      // zeroed
    int* dstCursor = p;                 p += Nn;
    int* rowStart  = p;                 p += Nn + 1;
    int* blkSum    = p;                 p += 64;
    int* csrKey    = p;                 p += E;
    p += ((8 - ((p - (int*)d_ws) & 7)) & 7);          // 32B-align
    __bf16* wbf = (__bf16*)p;           p += (WT_TOTAL + 1) / 2;
    __bf16* ca  = (__bf16*)p;                          // RR*Nn*HH bf16 = 25.6 MB

    hipFuncSetAttribute((const void*)k_mega,
                        hipFuncAttributeMaxDynamicSharedMemorySize,
                        DSMEM_ELEMS * (int)sizeof(__bf16));

    hipMemsetAsync(d_ws, 0, (size_t)(4 + Nn) * sizeof(int), stream);

    k_mega<<<DGRID, NT, DSMEM_ELEMS * sizeof(__bf16), stream>>>(
        nf, es, ed, et, Wr1, br1, Wr2, br2, Wr3, br3,
        Wn1, bn1, Wn2, bn2, Wn3, bn3,
        wbf, ca, bar, dstCnt, dstCursor, rowStart, blkSum, csrKey, out,
        Nn, E, NB);
}

// Round 6
// 365.964 us; speedup vs baseline: 1.1778x; 1.1778x over previous
//
#include <hip/hip_runtime.h>

#define DD 128
#define HH 64
#define RR 4
#define NT 256          // block size
#define DGRID 512       // persistent grid: 2 blocks/CU exactly (residency guaranteed)
#define DPART 128       // DGRID / RR tile-stride per relation (dense phase)

typedef __attribute__((ext_vector_type(8))) __bf16 bf16x8;
typedef __attribute__((ext_vector_type(4))) __bf16 bf16x4;
typedef __attribute__((ext_vector_type(4))) float f32x4;

// LDS row strides (bf16 elements). Odd multiples of 8 -> conflict-free b128 r/w.
#define SK128 136   // K=128 rows (+8 pad)
#define SK64  72    // K=64 rows  (+8 pad)
#define ABLK  2176  // per-wave act block

// dense-phase dynamic LDS layout (elements)
#define O_W1  0                    // 64 x 136 = 8704
#define O_W2  8704                 // 64 x 72  = 4608
#define O_W3  13312                // 128 x 72 = 9216
#define O_WP  22528                // 64 x 136 = 8704
#define O_ACT 31232                // 4 x 2176 = 8704
#define DSMEM_ELEMS 39936          // 79872 B -> 2 blocks/CU
// node-phase layout (same buffer, after grid barrier)
#define N_W1  0
#define N_W2  8704
#define N_W3  13312
#define N_ACT 22528                // + 4 x 2176 -> 31232 <= DSMEM_ELEMS

// global bf16 weight pool offsets (elements), all matrices [n][k] row-major
#define W1T_OFF 0        // [R][64][128]
#define W2T_OFF 32768    // [R][64][64]
#define W3T_OFF 49152    // [R][128][64]
#define WPT_OFF 81920    // [R][64][128]  (Wn1 slice 1+r)
#define WN1_OFF 114688   // [64][128]     (Wn1 slice 0)
#define WN2_OFF 122880   // [64][64]
#define WN3_OFF 126976   // [128][64]
#define WT_TOTAL 135168

#define MFMA(a, b, c) __builtin_amdgcn_mfma_f32_16x16x32_bf16(a, b, c, 0, 0, 0)

// ca column permutation: stored col' = ln*4 + nt -> 8B store in PROJ, 8B load in gather.

// ---- manual grid barrier. FENCE DISCIPLINE (the round-5 lesson):
// gfx950 agent-scope acquire = buffer_inv (whole-XCD L2 invalidate); release = buffer_wbl2
// (whole-L2 writeback). Round 5 polled with ACQUIRE -> an L2-invalidate PER POLL from every
// block = grid-wide invalidation storm (354us, MfmaUtil 1.5%). Correct discipline:
//   arrive : one RELEASE fetch_add  (one wbl2 per block -- the cross-XCD publish)
//   spin   : RELAXED atomic loads   (coherent-point read, NO cache-maintenance side effects)
//   exit   : one __threadfence()    (one buffer_inv per block -- see fresh data)
__device__ __forceinline__ void gbar(int* bar, int target) {
    __syncthreads();   // all block stores executed (compiler drains vmcnt before s_barrier)
    if (threadIdx.x == 0) {
        __hip_atomic_fetch_add(bar, 1, __ATOMIC_RELEASE, __HIP_MEMORY_SCOPE_AGENT);
        while (__hip_atomic_load(bar, __ATOMIC_RELAXED, __HIP_MEMORY_SCOPE_AGENT) < target)
            __builtin_amdgcn_s_sleep(2);
        __threadfence();   // single acquire: invalidate stale L1/L2 once
    }
    __syncthreads();
}

// Stage [ROWS][COLS] row-major global -> LDS rows with padded STRIDE.
template<int ROWS, int COLS, int STRIDE, int BLK>
__device__ __forceinline__ void stageRM(const __bf16* __restrict__ g, __bf16* s, int tid) {
    constexpr int CH = COLS / 8;
    constexpr int TOT = ROWS * CH;
    #pragma unroll
    for (int i = tid; i < TOT; i += BLK) {
        const int row = i / CH, c8 = i % CH;
        *(bf16x8*)(s + row * STRIDE + c8 * 8) = *(const bf16x8*)(g + row * COLS + c8 * 8);
    }
}

// ================= single persistent kernel: all phases, 5 manual grid barriers =================
__global__ __launch_bounds__(NT, 2) void k_mega(
    const float* __restrict__ nf,
    const int* __restrict__ es, const int* __restrict__ ed, const int* __restrict__ et,
    const float* __restrict__ Wr1, const float* __restrict__ br1,
    const float* __restrict__ Wr2, const float* __restrict__ br2,
    const float* __restrict__ Wr3, const float* __restrict__ br3,
    const float* __restrict__ Wn1, const float* __restrict__ bn1,
    const float* __restrict__ Wn2, const float* __restrict__ bn2,
    const float* __restrict__ Wn3, const float* __restrict__ bn3,
    __bf16* __restrict__ wt, __bf16* __restrict__ ca,
    int* bar, int* __restrict__ dstCnt, int* __restrict__ dstCursor,
    int* __restrict__ rowStart, int* __restrict__ blkSum,
    int* __restrict__ csrKey, float* __restrict__ out,
    int Nn, int E, int NB)
{
    extern __shared__ __bf16 smem[];

    const int tid  = threadIdx.x;
    const int gtid = blockIdx.x * NT + tid;
    const int GSZ  = DGRID * NT;                  // 131072
    const int w = tid >> 6;
    const int lane = tid & 63;
    const int ln = lane & 15, qd = lane >> 4;
    const int m0 = w << 4;

    // ---------- P0: weight transpose/convert (dstCnt + bar zeroed by host memset) ----------
    for (int i = gtid; i < WT_TOTAL; i += GSZ) {
        if (i < 32768) {                                  // Wr1 [r][k128][n64] -> [r][n][k]
            int r = i >> 13, k = (i >> 6) & 127, n = i & 63;
            wt[W1T_OFF + r * 8192 + n * 128 + k] = (__bf16)Wr1[i];
        } else if (i < 49152) {                           // Wr2 [r][k64][n64]
            int j = i - 32768; int r = j >> 12, k = (j >> 6) & 63, n = j & 63;
            wt[W2T_OFF + r * 4096 + n * 64 + k] = (__bf16)Wr2[j];
        } else if (i < 81920) {                           // Wr3 [r][k64][n128]
            int j = i - 49152; int r = j >> 13, k = (j >> 7) & 63, n = j & 127;
            wt[W3T_OFF + r * 8192 + n * 64 + k] = (__bf16)Wr3[j];
        } else if (i < 122880) {                          // Wn1 [(R+1)*128][64]
            int j = i - 81920; int row = j >> 6, n = j & 63;
            int s = row >> 7, k = row & 127;
            float v = Wn1[j];
            if (s == 0) wt[WN1_OFF + n * 128 + k] = (__bf16)v;
            else        wt[WPT_OFF + (s - 1) * 8192 + n * 128 + k] = (__bf16)v;
        } else if (i < 126976) {                          // Wn2 [k64][n64]
            int j = i - 122880; int k = j >> 6, n = j & 63;
            wt[WN2_OFF + n * 64 + k] = (__bf16)Wn2[j];
        } else {                                          // Wn3 [k64][n128]
            int j = i - 126976; int k = j >> 7, n = j & 127;
            wt[WN3_OFF + n * 64 + k] = (__bf16)Wn3[j];
        }
    }
    gbar(bar, DGRID * 1);   // ---- G1: weights visible

    // ---------- P1: dst histogram (atomics) + DENSE message/projection ----------
    for (int i = gtid; i < E; i += GSZ) atomicAdd(&dstCnt[ed[i]], 1);
    {
        const int r    = blockIdx.x & 3;
        const int part = blockIdx.x >> 2;
        __bf16* act = smem + O_ACT + w * ABLK;

        stageRM<64, 128, SK128, NT>(wt + W1T_OFF + r * 8192, smem + O_W1, tid);
        stageRM<64,  64, SK64 , NT>(wt + W2T_OFF + r * 4096, smem + O_W2, tid);
        stageRM<128, 64, SK64 , NT>(wt + W3T_OFF + r * 8192, smem + O_W3, tid);
        stageRM<64, 128, SK128, NT>(wt + WPT_OFF + r * 8192, smem + O_WP, tid);

        float bv1[4], bv2[4], bv3[8];
        #pragma unroll
        for (int nt = 0; nt < 4; nt++) {
            bv1[nt] = br1[r * HH + nt * 16 + ln];
            bv2[nt] = br2[r * HH + nt * 16 + ln];
        }
        #pragma unroll
        for (int nt = 0; nt < 8; nt++) bv3[nt] = br3[r * DD + nt * 16 + ln];

        const int T = (Nn + 63) >> 6;
        const int mx = tid >> 2, qx = tid & 3;
        __bf16* xr = act + (mx & 15) * SK128 + 32 * qx;

        float4 xv[8];
        int t = part;
        if (t < T) {
            const int node = min(t * 64 + mx, Nn - 1);
            const float4* rp = (const float4*)(nf + (size_t)node * DD) + 8 * qx;
            #pragma unroll
            for (int j = 0; j < 8; j++) xv[j] = rp[j];
        }
        __syncthreads();   // weights ready (block-local)

        for (; t < T; t += DPART) {
            const int nb0 = t * 64;
            #pragma unroll
            for (int jj = 0; jj < 4; jj++) {
                float4 v0 = xv[2 * jj], v1 = xv[2 * jj + 1];
                bf16x8 p;
                p[0] = (__bf16)v0.x; p[1] = (__bf16)v0.y; p[2] = (__bf16)v0.z; p[3] = (__bf16)v0.w;
                p[4] = (__bf16)v1.x; p[5] = (__bf16)v1.y; p[6] = (__bf16)v1.z; p[7] = (__bf16)v1.w;
                *(bf16x8*)(xr + 8 * jj) = p;
            }
            bf16x8 ax[4];
            #pragma unroll
            for (int i = 0; i < 4; i++)
                ax[i] = *(const bf16x8*)(act + ln * SK128 + i * 32 + 8 * qd);

            const int tn = t + DPART;
            if (tn < T) {
                const int node = min(tn * 64 + mx, Nn - 1);
                const float4* rp = (const float4*)(nf + (size_t)node * DD) + 8 * qx;
                #pragma unroll
                for (int j = 0; j < 8; j++) xv[j] = rp[j];
            }

            // GEMM1: K=128 N=64
            {
                f32x4 c[4] = {};
                #pragma unroll
                for (int kk = 0; kk < 4; kk++)
                    #pragma unroll
                    for (int nt = 0; nt < 4; nt++) {
                        bf16x8 b = *(const bf16x8*)(smem + O_W1 + (nt * 16 + ln) * SK128 + kk * 32 + 8 * qd);
                        c[nt] = MFMA(ax[kk], b, c[nt]);
                    }
                #pragma unroll
                for (int nt = 0; nt < 4; nt++)
                    #pragma unroll
                    for (int rg = 0; rg < 4; rg++) {
                        float v = c[nt][rg] + bv1[nt];
                        act[(qd * 4 + rg) * SK64 + nt * 16 + ln] = (__bf16)fmaxf(v, 0.f);
                    }
            }
            // GEMM2: K=64
            {
                bf16x8 a0 = *(const bf16x8*)(act + ln * SK64 + 0 + 8 * qd);
                bf16x8 a1 = *(const bf16x8*)(act + ln * SK64 + 32 + 8 * qd);
                f32x4 c[4] = {};
                #pragma unroll
                for (int nt = 0; nt < 4; nt++) {
                    bf16x8 b0 = *(const bf16x8*)(smem + O_W2 + (nt * 16 + ln) * SK64 + 0 + 8 * qd);
                    bf16x8 b1 = *(const bf16x8*)(smem + O_W2 + (nt * 16 + ln) * SK64 + 32 + 8 * qd);
                    c[nt] = MFMA(a0, b0, c[nt]);
                    c[nt] = MFMA(a1, b1, c[nt]);
                }
                #pragma unroll
                for (int nt = 0; nt < 4; nt++)
                    #pragma unroll
                    for (int rg = 0; rg < 4; rg++) {
                        float v = c[nt][rg] + bv2[nt];
                        act[(qd * 4 + rg) * SK64 + nt * 16 + ln] = (__bf16)fmaxf(v, 0.f);
                    }
            }
            // GEMM3: K=64 N=128
            {
                bf16x8 a0 = *(const bf16x8*)(act + ln * SK64 + 0 + 8 * qd);
                bf16x8 a1 = *(const bf16x8*)(act + ln * SK64 + 32 + 8 * qd);
                f32x4 c[8];
                #pragma unroll
                for (int nt = 0; nt < 8; nt++) {
                    bf16x8 b0 = *(const bf16x8*)(smem + O_W3 + (nt * 16 + ln) * SK64 + 0 + 8 * qd);
                    bf16x8 b1 = *(const bf16x8*)(smem + O_W3 + (nt * 16 + ln) * SK64 + 32 + 8 * qd);
                    f32x4 acc = {};
                    acc = MFMA(a0, b0, acc);
                    acc = MFMA(a1, b1, acc);
                    c[nt] = acc;
                }
                #pragma unroll
                for (int nt = 0; nt < 8; nt++)
                    #pragma unroll
                    for (int rg = 0; rg < 4; rg++) {
                        float v = c[nt][rg] + bv3[nt];
                        act[(qd * 4 + rg) * SK128 + nt * 16 + ln] = (__bf16)fmaxf(v, 0.f);
                    }
            }
            // PROJ: K=128 N=64 -> ca (permuted col ln*4+nt, 8B stores)
            {
                bf16x8 am[4];
                #pragma unroll
                for (int i = 0; i < 4; i++)
                    am[i] = *(const bf16x8*)(act + ln * SK128 + i * 32 + 8 * qd);
                f32x4 c[4] = {};
                #pragma unroll
                for (int kk = 0; kk < 4; kk++)
                    #pragma unroll
                    for (int nt = 0; nt < 4; nt++) {
                        bf16x8 b = *(const bf16x8*)(smem + O_WP + (nt * 16 + ln) * SK128 + kk * 32 + 8 * qd);
                        c[nt] = MFMA(am[kk], b, c[nt]);
                    }
                #pragma unroll
                for (int rg = 0; rg < 4; rg++) {
                    const int node = nb0 + m0 + qd * 4 + rg;
                    if (node < Nn) {
                        bf16x4 v;
                        v[0] = (__bf16)c[0][rg]; v[1] = (__bf16)c[1][rg];
                        v[2] = (__bf16)c[2][rg]; v[3] = (__bf16)c[3][rg];
                        *(bf16x4*)(ca + ((size_t)r * Nn + node) * HH + ln * 4) = v;
                    }
                }
            }
        }
    }
    gbar(bar, DGRID * 2);   // ---- G2: hist + ca complete

    // ---------- P2: per-chunk sums (blocks 0..NB-1, chunk = 1024 nodes) ----------
    if (blockIdx.x < NB) {
        int* iw = (int*)smem;
        const int g = blockIdx.x * 1024 + tid * 4;
        int s = 0;
        if (g + 3 < Nn) { int4 v = *(const int4*)(dstCnt + g); s = v.x + v.y + v.z + v.w; }
        else { for (int k = 0; k < 4; k++) if (g + k < Nn) s += dstCnt[g + k]; }
        for (int off = 32; off > 0; off >>= 1) s += __shfl_down(s, off);
        __syncthreads();                // claim LDS (dense weights dead)
        if ((tid & 63) == 0) iw[tid >> 6] = s;
        __syncthreads();
        if (tid == 0) blkSum[blockIdx.x] = iw[0] + iw[1] + iw[2] + iw[3];
    }
    gbar(bar, DGRID * 3);   // ---- G3: blkSum visible

    // ---------- P3: chunk-blocks redundantly scan blkSum; write rowStart/dstCursor ----------
    if (blockIdx.x < NB) {
        int* iw = (int*)smem;           // iw[0..3]=wave sums, iw[4]=chunk base
        if (tid < 64) {
            int s = (tid < NB) ? blkSum[tid] : 0;
            int sc = s;
            #pragma unroll
            for (int off = 1; off < 64; off <<= 1) { int u = __shfl_up(sc, off); if (tid >= off) sc += u; }
            int ex = (blockIdx.x == 0) ? 0 : __shfl(sc, blockIdx.x - 1);
            if (tid == 0) iw[4] = ex;
        }
        __syncthreads();
        const int e0base = iw[4];

        const int g = blockIdx.x * 1024 + tid * 4;
        int4 v = {0, 0, 0, 0};
        bool full = (g + 3 < Nn);
        if (full) v = *(const int4*)(dstCnt + g);
        else {
            if (g     < Nn) v.x = dstCnt[g];
            if (g + 1 < Nn) v.y = dstCnt[g + 1];
            if (g + 2 < Nn) v.z = dstCnt[g + 2];
        }
        int s = v.x + v.y + v.z + v.w;
        int lane2 = tid & 63, wv = tid >> 6;
        int sc = s;
        #pragma unroll
        for (int off = 1; off < 64; off <<= 1) { int u = __shfl_up(sc, off); if (lane2 >= off) sc += u; }
        if (lane2 == 63) iw[wv] = sc;
        __syncthreads();
        int wadd = 0;
        for (int i = 0; i < wv; i++) wadd += iw[i];
        int e0 = e0base + wadd + sc - s;
        int4 rs; rs.x = e0; rs.y = e0 + v.x; rs.z = rs.y + v.y; rs.w = rs.z + v.z;
        if (full) { *(int4*)(rowStart + g) = rs; *(int4*)(dstCursor + g) = rs; }
        else {
            int a[4] = {rs.x, rs.y, rs.z, rs.w};
            for (int k = 0; k < 4; k++) if (g + k < Nn) { rowStart[g + k] = a[k]; dstCursor[g + k] = a[k]; }
        }
    }
    if (gtid == 0) rowStart[Nn] = E;
    gbar(bar, DGRID * 4);   // ---- G4: rowStart/dstCursor visible

    // ---------- P4: CSR fill ----------
    for (int i = gtid; i < E; i += GSZ) {
        int sl = atomicAdd(&dstCursor[ed[i]], 1);
        csrKey[sl] = et[i] * Nn + es[i];
    }
    gbar(bar, DGRID * 5);   // ---- G5: csrKey complete

    // ---------- P5: node updater MLP (stage WN once, grid-stride tiles) ----------
    {
        __bf16* act = smem + N_ACT + w * ABLK;
        stageRM<64, 128, SK128, NT>(wt + WN1_OFF, smem + N_W1, tid);
        stageRM<64,  64, SK64 , NT>(wt + WN2_OFF, smem + N_W2, tid);
        stageRM<128, 64, SK64 , NT>(wt + WN3_OFF, smem + N_W3, tid);

        float bv1[4], bv2[4], bv3[8];
        #pragma unroll
        for (int nt = 0; nt < 4; nt++) { bv1[nt] = bn1[nt * 16 + ln]; bv2[nt] = bn2[nt * 16 + ln]; }
        #pragma unroll
        for (int nt = 0; nt < 8; nt++) bv3[nt] = bn3[nt * 16 + ln];

        const int T = (Nn + 63) >> 6;
        const int mx = tid >> 2, qx = tid & 3;
        __bf16* xr = act + (mx & 15) * SK128 + 32 * qx;
        __syncthreads();   // WN weights ready (block-local)

        for (int t = blockIdx.x; t < T; t += DGRID) {
            const int nb0 = t * 64;
            // relu(X) rows -> act (wave-local)
            {
                const int node = min(nb0 + mx, Nn - 1);
                const float4* rp = (const float4*)(nf + (size_t)node * DD) + 8 * qx;
                #pragma unroll
                for (int jj = 0; jj < 4; jj++) {
                    float4 v0 = rp[2 * jj], v1 = rp[2 * jj + 1];
                    bf16x8 p;
                    p[0] = (__bf16)fmaxf(v0.x, 0.f); p[1] = (__bf16)fmaxf(v0.y, 0.f);
                    p[2] = (__bf16)fmaxf(v0.z, 0.f); p[3] = (__bf16)fmaxf(v0.w, 0.f);
                    p[4] = (__bf16)fmaxf(v1.x, 0.f); p[5] = (__bf16)fmaxf(v1.y, 0.f);
                    p[6] = (__bf16)fmaxf(v1.z, 0.f); p[7] = (__bf16)fmaxf(v1.w, 0.f);
                    *(bf16x8*)(xr + 8 * jj) = p;
                }
            }
            bf16x8 ax[4];
            #pragma unroll
            for (int i = 0; i < 4; i++)
                ax[i] = *(const bf16x8*)(act + ln * SK128 + i * 32 + 8 * qd);

            // CSR gather (permuted ca: one 8B load per lane per edge; 4 rows x 2-edge ILP)
            float agg[4][4] = {};
            {
                const int base = nb0 + m0 + qd * 4;
                int rs[5];
                #pragma unroll
                for (int j = 0; j < 5; j++) rs[j] = rowStart[min(base + j, Nn)];
                int cur[4];
                #pragma unroll
                for (int rg = 0; rg < 4; rg++) cur[rg] = rs[rg];
                const __bf16* cab = ca + ln * 4;

                while (true) {
                    int k0[4], k1[4];
                    bool v0[4], v1[4];
                    bool any = false;
                    #pragma unroll
                    for (int rg = 0; rg < 4; rg++) {
                        const int c0 = cur[rg], e1 = rs[rg + 1];
                        v0[rg] = c0 < e1;
                        v1[rg] = c0 + 1 < e1;
                        if (v0[rg]) k0[rg] = csrKey[c0];
                        if (v1[rg]) k1[rg] = csrKey[c0 + 1];
                        cur[rg] = c0 + (v0[rg] ? 1 : 0) + (v1[rg] ? 1 : 0);
                        any |= v0[rg];
                    }
                    if (!any) break;
                    #pragma unroll
                    for (int rg = 0; rg < 4; rg++) {
                        if (v0[rg]) {
                            const bf16x4 x = *(const bf16x4*)(cab + (size_t)k0[rg] * HH);
                            agg[rg][0] += (float)x[0]; agg[rg][1] += (float)x[1];
                            agg[rg][2] += (float)x[2]; agg[rg][3] += (float)x[3];
                        }
                        if (v1[rg]) {
                            const bf16x4 x = *(const bf16x4*)(cab + (size_t)k1[rg] * HH);
                            agg[rg][0] += (float)x[0]; agg[rg][1] += (float)x[1];
                            agg[rg][2] += (float)x[2]; agg[rg][3] += (float)x[3];
                        }
                    }
                }
            }

            // GEMM1n: K=128 N=64 (+agg)
            {
                f32x4 c[4] = {};
                #pragma unroll
                for (int kk = 0; kk < 4; kk++)
                    #pragma unroll
                    for (int nt = 0; nt < 4; nt++) {
                        bf16x8 b = *(const bf16x8*)(smem + N_W1 + (nt * 16 + ln) * SK128 + kk * 32 + 8 * qd);
                        c[nt] = MFMA(ax[kk], b, c[nt]);
                    }
                #pragma unroll
                for (int nt = 0; nt < 4; nt++)
                    #pragma unroll
                    for (int rg = 0; rg < 4; rg++) {
                        float v = c[nt][rg] + bv1[nt] + agg[rg][nt];
                        act[(qd * 4 + rg) * SK64 + nt * 16 + ln] = (__bf16)fmaxf(v, 0.f);
                    }
            }
            // GEMM2n: K=64
            {
                bf16x8 a0 = *(const bf16x8*)(act + ln * SK64 + 0 + 8 * qd);
                bf16x8 a1 = *(const bf16x8*)(act + ln * SK64 + 32 + 8 * qd);
                f32x4 c[4] = {};
                #pragma unroll
                for (int nt = 0; nt < 4; nt++) {
                    bf16x8 b0 = *(const bf16x8*)(smem + N_W2 + (nt * 16 + ln) * SK64 + 0 + 8 * qd);
                    bf16x8 b1 = *(const bf16x8*)(smem + N_W2 + (nt * 16 + ln) * SK64 + 32 + 8 * qd);
                    c[nt] = MFMA(a0, b0, c[nt]);
                    c[nt] = MFMA(a1, b1, c[nt]);
                }
                #pragma unroll
                for (int nt = 0; nt < 4; nt++)
                    #pragma unroll
                    for (int rg = 0; rg < 4; rg++) {
                        float v = c[nt][rg] + bv2[nt];
                        act[(qd * 4 + rg) * SK64 + nt * 16 + ln] = (__bf16)fmaxf(v, 0.f);
                    }
            }
            // GEMM3n: K=64 N=128 -> out
            {
                bf16x8 a0 = *(const bf16x8*)(act + ln * SK64 + 0 + 8 * qd);
                bf16x8 a1 = *(const bf16x8*)(act + ln * SK64 + 32 + 8 * qd);
                f32x4 c[8];
                #pragma unroll
                for (int nt = 0; nt < 8; nt++) {
                    bf16x8 b0 = *(const bf16x8*)(smem + N_W3 + (nt * 16 + ln) * SK64 + 0 + 8 * qd);
                    bf16x8 b1 = *(const bf16x8*)(smem + N_W3 + (nt * 16 + ln) * SK64 + 32 + 8 * qd);
                    f32x4 acc = {};
                    acc = MFMA(a0, b0, acc);
                    acc = MFMA(a1, b1, acc);
                    c[nt] = acc;
                }
                #pragma unroll
                for (int rg = 0; rg < 4; rg++) {
                    const int node = nb0 + m0 + qd * 4 + rg;
                    if (node < Nn) {
                        float* op = out + (size_t)node * DD;
                        #pragma unroll
                        for (int nt = 0; nt < 8; nt++)
                            op[nt * 16 + ln] = c[nt][rg] + bv3[nt];
                    }
                }
            }
        }
    }
}

extern "C" void kernel_launch(void* const* d_in, const int* in_sizes, int n_in,
                              void* d_out, int out_size, void* d_ws, size_t ws_size,
                              hipStream_t stream) {
    const float* nf  = (const float*)d_in[0];
    const int*   es  = (const int*)d_in[1];
    const int*   ed  = (const int*)d_in[2];
    const int*   et  = (const int*)d_in[3];
    const float* Wr1 = (const float*)d_in[4];
    const float* br1 = (const float*)d_in[5];
    const float* Wr2 = (const float*)d_in[6];
    const float* br2 = (const float*)d_in[7];
    const float* Wr3 = (const float*)d_in[8];
    const float* br3 = (const float*)d_in[9];
    const float* Wn1 = (const float*)d_in[10];
    const float* bn1 = (const float*)d_in[11];
    const float* Wn2 = (const float*)d_in[12];
    const float* bn2 = (const float*)d_in[13];
    const float* Wn3 = (const float*)d_in[14];
    const float* bn3 = (const float*)d_in[15];
    float* out = (float*)d_out;

    int Nn = in_sizes[0] / DD;   // 50000
    int E  = in_sizes[1];        // 200000
    int NB = (Nn + 1023) / 1024; // 49

    int* p = (int*)d_ws;
    int* bar       = p;                 p += 4;       // barrier counter (zeroed)
    int* dstCnt    = p;                 p += Nn;      // zeroed
    int* dstCursor = p;                 p += Nn;
    int* rowStart  = p;                 p += Nn + 1;
    int* blkSum    = p;                 p += 64;
    int* csrKey    = p;                 p += E;
    p += ((8 - ((p - (int*)d_ws) & 7)) & 7);          // 32B-align
    __bf16* wbf = (__bf16*)p;           p += (WT_TOTAL + 1) / 2;
    __bf16* ca  = (__bf16*)p;                          // RR*Nn*HH bf16 = 25.6 MB

    hipFuncSetAttribute((const void*)k_mega,
                        hipFuncAttributeMaxDynamicSharedMemorySize,
                        DSMEM_ELEMS * (int)sizeof(__bf16));

    hipMemsetAsync(d_ws, 0, (size_t)(4 + Nn) * sizeof(int), stream);

    k_mega<<<DGRID, NT, DSMEM_ELEMS * sizeof(__bf16), stream>>>(
        nf, es, ed, et, Wr1, br1, Wr2, br2, Wr3, br3,
        Wn1, bn1, Wn2, bn2, Wn3, bn3,
        wbf, ca, bar, dstCnt, dstCursor, rowStart, blkSum, csrKey, out,
        Nn, E, NB);
}

// Round 9
// 193.374 us; speedup vs baseline: 2.2291x; 1.8925x over previous
//
#include <hip/hip_runtime.h>

#define DD 128
#define HH 64
#define RR 4
#define NT 256          // k_dense block
#define NNT 512         // k_node block (8 waves, 128 nodes)
#define DGRID 512       // k_dense grid: 2 blocks/CU
#define DPART 128       // parts per relation
#define MFMA(a, b, c) __builtin_amdgcn_mfma_f32_16x16x32_bf16(a, b, c, 0, 0, 0)

typedef __attribute__((ext_vector_type(8))) __bf16 bf16x8;
typedef __attribute__((ext_vector_type(4))) __bf16 bf16x4;
typedef __attribute__((ext_vector_type(4))) float f32x4;

// LDS row strides (bf16 elements). Odd multiples of 8 -> conflict-free b128 r/w.
#define SK128 136
#define SK64  72
#define ABLK  2176

// k_dense dynamic LDS layout (elements)
#define O_W1  0
#define O_W2  8704
#define O_W3  13312
#define O_WP  22528
#define O_ACT 31232
#define DSMEM_ELEMS 39936          // 79872 B -> 2 blocks/CU
// k_node dynamic LDS layout (8 waves of act)
#define N_W1  0
#define N_W2  8704
#define N_W3  13312
#define N_ACT 22528
#define NSMEM_ELEMS 39936

// global bf16 weight pool offsets (elements), all matrices [n][k] row-major
#define W1T_OFF 0
#define W2T_OFF 32768
#define W3T_OFF 49152
#define WPT_OFF 81920
#define WN1_OFF 114688
#define WN2_OFF 122880
#define WN3_OFF 126976
#define WT_TOTAL 135168

// ca column permutation: stored col' = ln*4 + nt -> 8B store in PROJ, 8B load in gather.

// FENCED small-grid barrier — round-5/6 correctness-proven discipline.
//   arrive : RELEASE fetch_add   (one wbl2 per block -- publishes prior plain stores)
//   spin   : RELAXED loads       (no cache-maintenance side effects)
//   exit   : one __threadfence() (one buffer_inv per block -- see others' data)
// Only the NB (~49) CSR blocks participate.
__device__ __forceinline__ void gbar(int* bar, int target) {
    __syncthreads();   // drains vmcnt: this block's prior stores are performed
    if (threadIdx.x == 0) {
        __hip_atomic_fetch_add(bar, 1, __ATOMIC_RELEASE, __HIP_MEMORY_SCOPE_AGENT);
        while (__hip_atomic_load(bar, __ATOMIC_RELAXED, __HIP_MEMORY_SCOPE_AGENT) < target)
            __builtin_amdgcn_s_sleep(1);
        __threadfence();
    }
    __syncthreads();
}

// Stage [ROWS][COLS] row-major global -> LDS rows with padded STRIDE.
template<int ROWS, int COLS, int STRIDE, int BLK>
__device__ __forceinline__ void stageRM(const __bf16* __restrict__ g, __bf16* s, int tid) {
    constexpr int CH = COLS / 8;
    constexpr int TOT = ROWS * CH;
    #pragma unroll
    for (int i = tid; i < TOT; i += BLK) {
        const int row = i / CH, c8 = i % CH;
        *(bf16x8*)(s + row * STRIDE + c8 * 8) = *(const bf16x8*)(g + row * COLS + c8 * 8);
    }
}

// ---------------- fused: dst histogram + weight transpose/convert ----------------
__global__ void k_prep_hist(const float* __restrict__ Wr1, const float* __restrict__ Wr2,
                            const float* __restrict__ Wr3, const float* __restrict__ Wn1,
                            const float* __restrict__ Wn2, const float* __restrict__ Wn3,
                            __bf16* __restrict__ wt,
                            const int* __restrict__ ed, int* __restrict__ dstCnt, int E) {
    int i = blockIdx.x * blockDim.x + threadIdx.x;
    if (i < E) atomicAdd(&dstCnt[ed[i]], 1);
    if (i < 32768) {                                  // Wr1 [r][k128][n64] -> [r][n][k]
        int r = i >> 13, k = (i >> 6) & 127, n = i & 63;
        wt[W1T_OFF + r * 8192 + n * 128 + k] = (__bf16)Wr1[i];
    } else if (i < 49152) {                           // Wr2 [r][k64][n64]
        int j = i - 32768; int r = j >> 12, k = (j >> 6) & 63, n = j & 63;
        wt[W2T_OFF + r * 4096 + n * 64 + k] = (__bf16)Wr2[j];
    } else if (i < 81920) {                           // Wr3 [r][k64][n128]
        int j = i - 49152; int r = j >> 13, k = (j >> 7) & 63, n = j & 127;
        wt[W3T_OFF + r * 8192 + n * 64 + k] = (__bf16)Wr3[j];
    } else if (i < 122880) {                          // Wn1 [(R+1)*128][64]
        int j = i - 81920; int row = j >> 6, n = j & 63;
        int s = row >> 7, k = row & 127;
        float v = Wn1[j];
        if (s == 0) wt[WN1_OFF + n * 128 + k] = (__bf16)v;
        else        wt[WPT_OFF + (s - 1) * 8192 + n * 128 + k] = (__bf16)v;
    } else if (i < 126976) {                          // Wn2 [k64][n64]
        int j = i - 122880; int k = j >> 6, n = j & 63;
        wt[WN2_OFF + n * 64 + k] = (__bf16)Wn2[j];
    } else if (i < WT_TOTAL) {                        // Wn3 [k64][n128]
        int j = i - 126976; int k = j >> 7, n = j & 127;
        wt[WN3_OFF + n * 64 + k] = (__bf16)Wn3[j];
    }
}

// ------- dense kernel: CSR build in leading NB blocks (overlapped) + STATIC tile partition -------
// Round-7/8 bug: per-THREAD atomicAdd tile claim gave each lane a different tile (compiler
// coalesces atomicAdd(p,1) to base+mbcnt per lane, m20) -> Frankenstein tiles -> ~3e-3 error.
// Fix: static part = 127 - (bid>>2). T=782=6*128+14: parts 0..13 carry 7 tiles -> remap hands
// the 7-tile parts to non-CSR blocks; CSR-prologue blocks (bid<NB -> old parts 0..12) get 6.
__global__ __launch_bounds__(NT, 2) void k_dense(
    const float* __restrict__ nf,
    const int* __restrict__ es, const int* __restrict__ ed, const int* __restrict__ et,
    const float* __restrict__ br1, const float* __restrict__ br2, const float* __restrict__ br3,
    const __bf16* __restrict__ wt, __bf16* __restrict__ ca,
    int* bar, const int* __restrict__ dstCnt, int* dstCursor,
    int* __restrict__ rowStart, int* blkSum, int* __restrict__ csrKey,
    int Nn, int E, int NB)
{
    extern __shared__ __bf16 smem[];
    const int bid = blockIdx.x;
    const int r   = bid & 3;
    const int part = (DPART - 1) - (bid >> 2);   // CSR blocks -> high parts -> fewer tiles
    const int tid = threadIdx.x;
    const int w = tid >> 6;
    const int lane = tid & 63;
    const int ln = lane & 15, qd = lane >> 4;
    const int m0 = w << 4;
    __bf16* act = smem + O_ACT + w * ABLK;

    // ---- weight staging issued first (in flight during CSR prologue / bias loads)
    stageRM<64, 128, SK128, NT>(wt + W1T_OFF + r * 8192, smem + O_W1, tid);
    stageRM<64,  64, SK64 , NT>(wt + W2T_OFF + r * 4096, smem + O_W2, tid);
    stageRM<128, 64, SK64 , NT>(wt + W3T_OFF + r * 8192, smem + O_W3, tid);
    stageRM<64, 128, SK128, NT>(wt + WPT_OFF + r * 8192, smem + O_WP, tid);

    // ================= CSR prologue: blocks 0..NB-1 only (others go straight to GEMM) ======
    if (bid < NB) {
        int* iw = (int*)(smem + O_ACT);        // scratch ints in act region (dead until GEMM)
        // ---- phase A: per-chunk counts + local scan
        const int g = bid * 1024 + tid * 4;
        int4 v = {0, 0, 0, 0};
        const bool full = (g + 3 < Nn);
        if (full) v = *(const int4*)(dstCnt + g);
        else {
            if (g     < Nn) v.x = dstCnt[g];
            if (g + 1 < Nn) v.y = dstCnt[g + 1];
            if (g + 2 < Nn) v.z = dstCnt[g + 2];
        }
        const int s = v.x + v.y + v.z + v.w;
        int sc = s;
        #pragma unroll
        for (int off = 1; off < 64; off <<= 1) { int u = __shfl_up(sc, off); if (lane >= off) sc += u; }
        if (lane == 63) iw[w] = sc;
        __syncthreads();
        int wadd = 0;
        for (int i = 0; i < w; i++) wadd += iw[i];
        if (tid == 0) blkSum[bid] = iw[0] + iw[1] + iw[2] + iw[3];
        gbar(bar, NB);                         // publishes blkSum; refreshes caches
        // ---- phase B: prefix over chunk totals + write rowStart / init dstCursor
        if (tid < 64) {
            int sb = (tid < NB) ? blkSum[tid] : 0;
            int scb = sb;
            #pragma unroll
            for (int off = 1; off < 64; off <<= 1) { int u = __shfl_up(scb, off); if (tid >= off) scb += u; }
            int ex = __shfl(scb, bid > 0 ? bid - 1 : 0);
            if (tid == 0) iw[8] = (bid > 0) ? ex : 0;
        }
        __syncthreads();
        const int e0 = iw[8] + wadd + sc - s;
        int4 rs; rs.x = e0; rs.y = e0 + v.x; rs.z = rs.y + v.y; rs.w = rs.z + v.z;
        if (full) {
            *(int4*)(rowStart + g) = rs;       // read only by k_node (next dispatch)
            *(int4*)(dstCursor + g) = rs;      // published by next gbar's release
        } else {
            int a[4] = {rs.x, rs.y, rs.z, rs.w};
            for (int k = 0; k < 4; k++) if (g + k < Nn) {
                rowStart[g + k] = a[k];
                dstCursor[g + k] = a[k];
            }
        }
        if (bid == 0 && tid == 0) rowStart[Nn] = E;
        gbar(bar, 2 * NB);                     // all cursors published + caches refreshed
        // ---- phase C: CSR fill (edge-parallel over the NB blocks; RMW at coherent point)
        for (int i = bid * NT + tid; i < E; i += NB * NT) {
            int sl = atomicAdd(&dstCursor[ed[i]], 1);
            csrKey[sl] = et[i] * Nn + es[i];   // read by k_node (next dispatch)
        }
    }

    // ================= dense message+projection, static tile partition =========
    float bv1[4], bv2[4], bv3[8];
    #pragma unroll
    for (int nt = 0; nt < 4; nt++) {
        bv1[nt] = br1[r * HH + nt * 16 + ln];
        bv2[nt] = br2[r * HH + nt * 16 + ln];
    }
    #pragma unroll
    for (int nt = 0; nt < 8; nt++) bv3[nt] = br3[r * DD + nt * 16 + ln];

    const int T = (Nn + 63) >> 6;
    const int mx = tid >> 2, qx = tid & 3;
    __bf16* xr = act + (mx & 15) * SK128 + 32 * qx;

    int t = part;
    float4 xv[8];
    if (t < T) {
        const int node = min(t * 64 + mx, Nn - 1);
        const float4* rp = (const float4*)(nf + (size_t)node * DD) + 8 * qx;
        #pragma unroll
        for (int j = 0; j < 8; j++) xv[j] = rp[j];
    }
    __syncthreads();   // weights staged (CSR blocks: also orders act-scratch reuse)

    for (; t < T; t += DPART) {
        const int nb0 = t * 64;
        // ---- X regs -> LDS (wave-local), extract A-frags
        #pragma unroll
        for (int jj = 0; jj < 4; jj++) {
            float4 v0 = xv[2 * jj], v1 = xv[2 * jj + 1];
            bf16x8 p;
            p[0] = (__bf16)v0.x; p[1] = (__bf16)v0.y; p[2] = (__bf16)v0.z; p[3] = (__bf16)v0.w;
            p[4] = (__bf16)v1.x; p[5] = (__bf16)v1.y; p[6] = (__bf16)v1.z; p[7] = (__bf16)v1.w;
            *(bf16x8*)(xr + 8 * jj) = p;
        }
        bf16x8 ax[4];
        #pragma unroll
        for (int i = 0; i < 4; i++)
            ax[i] = *(const bf16x8*)(act + ln * SK128 + i * 32 + 8 * qd);

        // ---- prefetch NEXT tile's X during the GEMMs
        const int tn = t + DPART;
        if (tn < T) {
            const int node = min(tn * 64 + mx, Nn - 1);
            const float4* rp = (const float4*)(nf + (size_t)node * DD) + 8 * qx;
            #pragma unroll
            for (int j = 0; j < 8; j++) xv[j] = rp[j];
        }

        // GEMM1: K=128 N=64
        {
            f32x4 c[4] = {};
            #pragma unroll
            for (int kk = 0; kk < 4; kk++)
                #pragma unroll
                for (int nt = 0; nt < 4; nt++) {
                    bf16x8 b = *(const bf16x8*)(smem + O_W1 + (nt * 16 + ln) * SK128 + kk * 32 + 8 * qd);
                    c[nt] = MFMA(ax[kk], b, c[nt]);
                }
            #pragma unroll
            for (int nt = 0; nt < 4; nt++)
                #pragma unroll
                for (int rg = 0; rg < 4; rg++) {
                    float v = c[nt][rg] + bv1[nt];
                    act[(qd * 4 + rg) * SK64 + nt * 16 + ln] = (__bf16)fmaxf(v, 0.f);
                }
        }
        // GEMM2: K=64
        {
            bf16x8 a0 = *(const bf16x8*)(act + ln * SK64 + 0 + 8 * qd);
            bf16x8 a1 = *(const bf16x8*)(act + ln * SK64 + 32 + 8 * qd);
            f32x4 c[4] = {};
            #pragma unroll
            for (int nt = 0; nt < 4; nt++) {
                bf16x8 b0 = *(const bf16x8*)(smem + O_W2 + (nt * 16 + ln) * SK64 + 0 + 8 * qd);
                bf16x8 b1 = *(const bf16x8*)(smem + O_W2 + (nt * 16 + ln) * SK64 + 32 + 8 * qd);
                c[nt] = MFMA(a0, b0, c[nt]);
                c[nt] = MFMA(a1, b1, c[nt]);
            }
            #pragma unroll
            for (int nt = 0; nt < 4; nt++)
                #pragma unroll
                for (int rg = 0; rg < 4; rg++) {
                    float v = c[nt][rg] + bv2[nt];
                    act[(qd * 4 + rg) * SK64 + nt * 16 + ln] = (__bf16)fmaxf(v, 0.f);
                }
        }
        // GEMM3: K=64 N=128
        {
            bf16x8 a0 = *(const bf16x8*)(act + ln * SK64 + 0 + 8 * qd);
            bf16x8 a1 = *(const bf16x8*)(act + ln * SK64 + 32 + 8 * qd);
            f32x4 c[8];
            #pragma unroll
            for (int nt = 0; nt < 8; nt++) {
                bf16x8 b0 = *(const bf16x8*)(smem + O_W3 + (nt * 16 + ln) * SK64 + 0 + 8 * qd);
                bf16x8 b1 = *(const bf16x8*)(smem + O_W3 + (nt * 16 + ln) * SK64 + 32 + 8 * qd);
                f32x4 acc = {};
                acc = MFMA(a0, b0, acc);
                acc = MFMA(a1, b1, acc);
                c[nt] = acc;
            }
            #pragma unroll
            for (int nt = 0; nt < 8; nt++)
                #pragma unroll
                for (int rg = 0; rg < 4; rg++) {
                    float v = c[nt][rg] + bv3[nt];
                    act[(qd * 4 + rg) * SK128 + nt * 16 + ln] = (__bf16)fmaxf(v, 0.f);
                }
        }
        // PROJ: K=128 N=64 -> ca (permuted col ln*4+nt, 8B stores)
        {
            bf16x8 am[4];
            #pragma unroll
            for (int i = 0; i < 4; i++)
                am[i] = *(const bf16x8*)(act + ln * SK128 + i * 32 + 8 * qd);
            f32x4 c[4] = {};
            #pragma unroll
            for (int kk = 0; kk < 4; kk++)
                #pragma unroll
                for (int nt = 0; nt < 4; nt++) {
                    bf16x8 b = *(const bf16x8*)(smem + O_WP + (nt * 16 + ln) * SK128 + kk * 32 + 8 * qd);
                    c[nt] = MFMA(am[kk], b, c[nt]);
                }
            #pragma unroll
            for (int rg = 0; rg < 4; rg++) {
                const int node = nb0 + m0 + qd * 4 + rg;
                if (node < Nn) {
                    bf16x4 vv;
                    vv[0] = (__bf16)c[0][rg]; vv[1] = (__bf16)c[1][rg];
                    vv[2] = (__bf16)c[2][rg]; vv[3] = (__bf16)c[3][rg];
                    *(bf16x4*)(ca + ((size_t)r * Nn + node) * HH + ln * 4) = vv;
                }
            }
        }
    }
}

// ---------------- node updater MLP (unchanged from round-3 passing version) ----------------
__global__ __launch_bounds__(NNT, 4) void k_node(
    const float* __restrict__ nf,
    const float* __restrict__ bn1, const float* __restrict__ bn2, const float* __restrict__ bn3,
    const __bf16* __restrict__ wt, const __bf16* __restrict__ ca,
    const int* __restrict__ rowStart, const int* __restrict__ csrKey,
    float* __restrict__ out, int Nn)
{
    extern __shared__ __bf16 smem[];
    const int nb0 = blockIdx.x * 128;
    const int tid = threadIdx.x;
    const int w = tid >> 6;
    const int lane = tid & 63;
    const int ln = lane & 15, qd = lane >> 4;
    const int m0 = w << 4;
    __bf16* act = smem + N_ACT + w * ABLK;

    stageRM<64, 128, SK128, NNT>(wt + WN1_OFF, smem + N_W1, tid);
    stageRM<64,  64, SK64 , NNT>(wt + WN2_OFF, smem + N_W2, tid);
    stageRM<128, 64, SK64 , NNT>(wt + WN3_OFF, smem + N_W3, tid);
    {
        const int m = tid >> 2, q = tid & 3;
        const int node = min(nb0 + m, Nn - 1);
        const float4* rp = (const float4*)(nf + (size_t)node * DD) + 8 * q;
        __bf16* xr = act + (m & 15) * SK128 + 32 * q;
        #pragma unroll
        for (int jj = 0; jj < 4; jj++) {
            float4 v0 = rp[2 * jj], v1 = rp[2 * jj + 1];
            bf16x8 p;
            p[0] = (__bf16)fmaxf(v0.x, 0.f); p[1] = (__bf16)fmaxf(v0.y, 0.f);
            p[2] = (__bf16)fmaxf(v0.z, 0.f); p[3] = (__bf16)fmaxf(v0.w, 0.f);
            p[4] = (__bf16)fmaxf(v1.x, 0.f); p[5] = (__bf16)fmaxf(v1.y, 0.f);
            p[6] = (__bf16)fmaxf(v1.z, 0.f); p[7] = (__bf16)fmaxf(v1.w, 0.f);
            *(bf16x8*)(xr + 8 * jj) = p;
        }
    }
    bf16x8 ax[4];
    #pragma unroll
    for (int i = 0; i < 4; i++)
        ax[i] = *(const bf16x8*)(act + ln * SK128 + i * 32 + 8 * qd);

    float bv1[4], bv2[4], bv3[8];
    #pragma unroll
    for (int nt = 0; nt < 4; nt++) { bv1[nt] = bn1[nt * 16 + ln]; bv2[nt] = bn2[nt * 16 + ln]; }
    #pragma unroll
    for (int nt = 0; nt < 8; nt++) bv3[nt] = bn3[nt * 16 + ln];

    // CSR gather (permuted ca: one 8B load per lane per edge; 4 rows x 2-edge ILP)
    float agg[4][4] = {};
    {
        const int base = nb0 + m0 + qd * 4;
        int rs[5];
        #pragma unroll
        for (int j = 0; j < 5; j++) rs[j] = rowStart[min(base + j, Nn)];
        int cur[4];
        #pragma unroll
        for (int rg = 0; rg < 4; rg++) cur[rg] = rs[rg];
        const __bf16* cab = ca + ln * 4;

        while (true) {
            int k0[4], k1[4];
            bool v0[4], v1[4];
            bool any = false;
            #pragma unroll
            for (int rg = 0; rg < 4; rg++) {
                const int c0 = cur[rg], e1 = rs[rg + 1];
                v0[rg] = c0 < e1;
                v1[rg] = c0 + 1 < e1;
                if (v0[rg]) k0[rg] = csrKey[c0];
                if (v1[rg]) k1[rg] = csrKey[c0 + 1];
                cur[rg] = c0 + (v0[rg] ? 1 : 0) + (v1[rg] ? 1 : 0);
                any |= v0[rg];
            }
            if (!any) break;
            #pragma unroll
            for (int rg = 0; rg < 4; rg++) {
                if (v0[rg]) {
                    const bf16x4 x = *(const bf16x4*)(cab + (size_t)k0[rg] * HH);
                    agg[rg][0] += (float)x[0]; agg[rg][1] += (float)x[1];
                    agg[rg][2] += (float)x[2]; agg[rg][3] += (float)x[3];
                }
                if (v1[rg]) {
                    const bf16x4 x = *(const bf16x4*)(cab + (size_t)k1[rg] * HH);
                    agg[rg][0] += (float)x[0]; agg[rg][1] += (float)x[1];
                    agg[rg][2] += (float)x[2]; agg[rg][3] += (float)x[3];
                }
            }
        }
    }
    __syncthreads();   // weights ready

    // GEMM1n: K=128 N=64 (+agg)
    {
        f32x4 c[4] = {};
        #pragma unroll
        for (int kk = 0; kk < 4; kk++)
            #pragma unroll
            for (int nt = 0; nt < 4; nt++) {
                bf16x8 b = *(const bf16x8*)(smem + N_W1 + (nt * 16 + ln) * SK128 + kk * 32 + 8 * qd);
                c[nt] = MFMA(ax[kk], b, c[nt]);
            }
        #pragma unroll
        for (int nt = 0; nt < 4; nt++)
            #pragma unroll
            for (int rg = 0; rg < 4; rg++) {
                float v = c[nt][rg] + bv1[nt] + agg[rg][nt];
                act[(qd * 4 + rg) * SK64 + nt * 16 + ln] = (__bf16)fmaxf(v, 0.f);
            }
    }
    // GEMM2n: K=64
    {
        bf16x8 a0 = *(const bf16x8*)(act + ln * SK64 + 0 + 8 * qd);
        bf16x8 a1 = *(const bf16x8*)(act + ln * SK64 + 32 + 8 * qd);
        f32x4 c[4] = {};
        #pragma unroll
        for (int nt = 0; nt < 4; nt++) {
            bf16x8 b0 = *(const bf16x8*)(smem + N_W2 + (nt * 16 + ln) * SK64 + 0 + 8 * qd);
            bf16x8 b1 = *(const bf16x8*)(smem + N_W2 + (nt * 16 + ln) * SK64 + 32 + 8 * qd);
            c[nt] = MFMA(a0, b0, c[nt]);
            c[nt] = MFMA(a1, b1, c[nt]);
        }
        #pragma unroll
        for (int nt = 0; nt < 4; nt++)
            #pragma unroll
            for (int rg = 0; rg < 4; rg++) {
                float v = c[nt][rg] + bv2[nt];
                act[(qd * 4 + rg) * SK64 + nt * 16 + ln] = (__bf16)fmaxf(v, 0.f);
            }
    }
    // GEMM3n: K=64 N=128 -> out
    {
        bf16x8 a0 = *(const bf16x8*)(act + ln * SK64 + 0 + 8 * qd);
        bf16x8 a1 = *(const bf16x8*)(act + ln * SK64 + 32 + 8 * qd);
        f32x4 c[8];
        #pragma unroll
        for (int nt = 0; nt < 8; nt++) {
            bf16x8 b0 = *(const bf16x8*)(smem + N_W3 + (nt * 16 + ln) * SK64 + 0 + 8 * qd);
            bf16x8 b1 = *(const bf16x8*)(smem + N_W3 + (nt * 16 + ln) * SK64 + 32 + 8 * qd);
            f32x4 acc = {};
            acc = MFMA(a0, b0, acc);
            acc = MFMA(a1, b1, acc);
            c[nt] = acc;
        }
        #pragma unroll
        for (int rg = 0; rg < 4; rg++) {
            const int node = nb0 + m0 + qd * 4 + rg;
            if (node < Nn) {
                float* op = out + (size_t)node * DD;
                #pragma unroll
                for (int nt = 0; nt < 8; nt++)
                    op[nt * 16 + ln] = c[nt][rg] + bv3[nt];
            }
        }
    }
}

extern "C" void kernel_launch(void* const* d_in, const int* in_sizes, int n_in,
                              void* d_out, int out_size, void* d_ws, size_t ws_size,
                              hipStream_t stream) {
    const float* nf  = (const float*)d_in[0];
    const int*   es  = (const int*)d_in[1];
    const int*   ed  = (const int*)d_in[2];
    const int*   et  = (const int*)d_in[3];
    const float* Wr1 = (const float*)d_in[4];
    const float* br1 = (const float*)d_in[5];
    const float* Wr2 = (const float*)d_in[6];
    const float* br2 = (const float*)d_in[7];
    const float* Wr3 = (const float*)d_in[8];
    const float* br3 = (const float*)d_in[9];
    const float* Wn1 = (const float*)d_in[10];
    const float* bn1 = (const float*)d_in[11];
    const float* Wn2 = (const float*)d_in[12];
    const float* bn2 = (const float*)d_in[13];
    const float* Wn3 = (const float*)d_in[14];
    const float* bn3 = (const float*)d_in[15];
    float* out = (float*)d_out;

    int Nn = in_sizes[0] / DD;   // 50000
    int E  = in_sizes[1];        // 200000
    int NB = (Nn + 1023) / 1024; // 49

    int* p = (int*)d_ws;
    int* bar       = p;                 p += 4;       // zeroed
    int* dstCnt    = p;                 p += Nn;      // zeroed
    int* dstCursor = p;                 p += Nn;
    int* rowStart  = p;                 p += Nn + 1;
    int* blkSum    = p;                 p += 64;
    int* csrKey    = p;                 p += E;
    p += ((8 - ((p - (int*)d_ws) & 7)) & 7);          // 32B-align
    __bf16* wbf = (__bf16*)p;           p += (WT_TOTAL + 1) / 2;
    __bf16* ca  = (__bf16*)p;                          // RR*Nn*HH bf16 = 25.6 MB

    hipFuncSetAttribute((const void*)k_dense,
                        hipFuncAttributeMaxDynamicSharedMemorySize,
                        DSMEM_ELEMS * (int)sizeof(__bf16));
    hipFuncSetAttribute((const void*)k_node,
                        hipFuncAttributeMaxDynamicSharedMemorySize,
                        NSMEM_ELEMS * (int)sizeof(__bf16));

    hipMemsetAsync(d_ws, 0, (size_t)(4 + Nn) * sizeof(int), stream);

    const int nb = (E + NT - 1) / NT;
    k_prep_hist<<<nb, NT, 0, stream>>>(Wr1, Wr2, Wr3, Wn1, Wn2, Wn3, wbf, ed, dstCnt, E);

    k_dense<<<DGRID, NT, DSMEM_ELEMS * sizeof(__bf16), stream>>>(
        nf, es, ed, et, br1, br2, br3, wbf, ca,
        bar, dstCnt, dstCursor, rowStart, blkSum, csrKey, Nn, E, NB);

    k_node<<<(Nn + 127) / 128, NNT, NSMEM_ELEMS * sizeof(__bf16), stream>>>(
        nf, bn1, bn2, bn3, wbf, ca, rowStart, csrKey, out, Nn);
}